// Round 1
// 4190.070 us; speedup vs baseline: 1.0622x; 1.0622x over previous
//
#include <hip/hip_runtime.h>
#include <hip/hip_bf16.h>

// Problem constants
#define HH     1024
#define BB     64
#define DIN    768
#define TAUD   500
#define LSTEPS 127      // 1 audio step + 126 one-hot steps
#define G4     4096
#define NB     256      // lstm blocks; each owns 4 j-columns (16 gate rows)
#define BHH    (BB*HH)
#define GST    17       // gates LDS row stride (16 + 1 pad)

typedef __attribute__((ext_vector_type(8))) short bf16x8;
typedef __attribute__((ext_vector_type(4))) float f32x4;
typedef unsigned short u16;
typedef unsigned long long u64;

__device__ __forceinline__ u16 f2b(float x){
  __hip_bfloat16 h = __float2bfloat16(x);
  return __builtin_bit_cast(u16, h);
}
__device__ __forceinline__ float b2f(u16 u){
  unsigned int x = ((unsigned int)u) << 16;
  return __builtin_bit_cast(float, x);
}
__device__ __forceinline__ float sig_(float x){ return 1.0f/(1.0f+__expf(-x)); }
__device__ __forceinline__ float tanh_(float x){
  float ax = fabsf(x);
  float e  = __expf(-2.0f*ax);
  float t  = (1.0f-e)/(1.0f+e);
  return x < 0.0f ? -t : t;
}

// ---------------- workspace layout (bytes), ~53 MB ------------------------
// R4: weights are pinned in LDS (128 KB/block: 4 packed matrices incl. W_ih0,
// whose LDS copy also serves the one-hot gather -> WG table deleted). The old
// per-step 24 MB weight stream (cyclic L2 thrash at ~850 GB/s = 28 us/step,
// the entire measured step time) is gone. h-state: system-scope (sc0 sc1,
// write-through) STORES so L2 never holds dirty h lines, normal cached READS
// made safe by an agent-scope acquire fence (per-XCD L2 invalidate) at the
// grid barrier -- harmless now that L2 holds no weights (R2's poison inverted).
constexpr size_t O_PACK  = 0;                                 // u16 [256][4][32 ktg][16 col][32 r]
constexpr size_t O_WOHI  = O_PACK + (size_t)NB*4*16384*2;     // bf16 [1024,1024]
constexpr size_t O_WOLO  = O_WOHI + (size_t)HH*HH*2;
constexpr size_t O_B0P   = O_WOLO + (size_t)HH*HH*2;          // f32 [1024 unit][4 g]
constexpr size_t O_B1P   = O_B0P  + G4*4;
constexpr size_t O_MEAN  = O_B1P  + G4*4;                     // f32 [64,768]
constexpr size_t O_X0    = O_MEAN + (size_t)BB*DIN*4;         // bf16 [64,1024]
constexpr size_t O_H0    = O_X0   + (size_t)BHH*2;            // bf16 [2][64][1024]
constexpr size_t O_H1    = O_H0   + (size_t)2*BHH*2;
constexpr size_t O_HS    = O_H1   + (size_t)2*BHH*2;          // bf16 [127][64][1024]
constexpr size_t O_BAR   = O_HS   + (size_t)LSTEPS*BHH*2;     // 512 ints

// ---------------- init: zero h states + barrier ---------------------------
__global__ void init_kernel(u16* h0, u16* h1, int* bar){
  int i = blockIdx.x*256 + threadIdx.x;
  int st = gridDim.x*256;
  for (int k=i;k<2*BHH;k+=st){ h0[k]=0; h1[k]=0; }
  if (i < 512) bar[i] = 0;
}

// ---------------- audio mean-pool (mean is linear: pool before project) ---
__global__ void pool_kernel(const float* __restrict__ audio, float* __restrict__ mean){
  int b = blockIdx.x/3, dc = blockIdx.x%3;
  int d = dc*256 + threadIdx.x;
  const float* p = audio + (size_t)b*TAUD*DIN + d;
  float s = 0.f;
  #pragma unroll 5
  for (int t=0;t<TAUD;++t) s += p[(size_t)t*DIN];
  mean[b*DIN + d] = s*(1.0f/TAUD);
}

// ---------------- project pooled audio: x0[b,h] (fp32 math, bf16 out) -----
__global__ void project_kernel(const float* __restrict__ mean, const float* __restrict__ Wp,
                               const float* __restrict__ bp, u16* __restrict__ x0){
  __shared__ float wrow[DIN];
  __shared__ float part[256];
  int h = blockIdx.x;
  for (int i=threadIdx.x;i<DIN;i+=256) wrow[i] = Wp[(size_t)h*DIN + i];
  __syncthreads();
  int b = threadIdx.x>>2, q = threadIdx.x&3;
  const float* mr = mean + b*DIN + q*192;
  const float* wr = wrow + q*192;
  float s = 0.f;
  #pragma unroll 8
  for (int i=0;i<192;++i) s += mr[i]*wr[i];
  part[threadIdx.x] = s;
  __syncthreads();
  if (q==0){
    float v = part[threadIdx.x]+part[threadIdx.x+1]+part[threadIdx.x+2]+part[threadIdx.x+3] + bp[h];
    x0[b*HH + h] = f2b(v);
  }
}

// ---------------- pack all 4 weight matrices into per-block blobs ---------
// Per (bid,m): 16384 u16 = [32 ktg][16 col][32 r]; element = Wm[ng][ktg*32+r],
// ng = bid*4 + (col&3) + (col>>2)*1024. Per MFMA k-step a wave reads one
// contiguous 1KB line (conflict-free ds_read_b128). m: 0=Wih0 1=Whh0 2=Wih1 3=Whh1.
__global__ void pack_w_kernel(const float* __restrict__ Wih0, const float* __restrict__ Whh0,
                              const float* __restrict__ Wih1, const float* __restrict__ Whh1,
                              u16* __restrict__ P){
  int bid = blockIdx.x, m = blockIdx.y;
  const float* src = (m==0)? Wih0 : (m==1)? Whh0 : (m==2)? Wih1 : Whh1;
  u16* dst = P + ((size_t)bid*4 + m)*16384;
  for (int e = threadIdx.x; e < 16384; e += 256){
    int r = e&31, col = (e>>5)&15, ktg = e>>9;
    int ng = bid*4 + (col&3) + (col>>2)*HH;
    dst[e] = f2b(src[(size_t)ng*HH + ktg*32 + r]);
  }
}

// Packed biases: Bp[(bid*4+jj)*4+g] = b_ih[n]+b_hh[n], n = bid*4+jj+g*1024
__global__ void pack_bias_kernel(const float* bih0, const float* bhh0,
                                 const float* bih1, const float* bhh1,
                                 float* B0p, float* B1p){
  int i = blockIdx.x*256 + threadIdx.x;
  if (i < G4){
    int n = (i>>2) + (i&3)*HH;
    B0p[i] = bih0[n]+bhh0[n];
    B1p[i] = bih1[n]+bhh1[n];
  }
}

// W_out split into bf16 hi + lo for extra precision on final GEMM
__global__ void wout_kernel(const float* __restrict__ src, u16* __restrict__ hi,
                            u16* __restrict__ lo, int n){
  int i = blockIdx.x*256+threadIdx.x, st = gridDim.x*256;
  for (;i<n;i+=st){
    float v = src[i];
    u16 h = f2b(v);
    hi[i] = h;
    lo[i] = f2b(v - b2f(h));
  }
}

// ---------------- system-scope (cache-bypass, write-through) store --------
__device__ __forceinline__ void sysst32(unsigned* p, unsigned v){
  __hip_atomic_store(p, v, __ATOMIC_RELAXED, __HIP_MEMORY_SCOPE_SYSTEM);
}

// relaxed 2-level tree barrier (16 leaves x 16 blocks) + agent-acquire fence.
// The fence invalidates vL1 + per-XCD L2 so subsequent NORMAL h loads see the
// system-scope stores from other XCDs. Safe: lstm_kernel issues no plain
// global stores at all, so L2 never holds dirty lines the inv could lose.
__device__ __forceinline__ void gridbar(int* bar, int t){
  __syncthreads();   // drains vmcnt(0): all sc0sc1 h-stores at coherence point
  if (threadIdx.x==0){
    int leaf = blockIdx.x>>4;
    int a = __hip_atomic_fetch_add(&bar[leaf*32], 1, __ATOMIC_RELAXED, __HIP_MEMORY_SCOPE_SYSTEM);
    if (a == t*16 + 15)
      __hip_atomic_fetch_add(&bar[511], 1, __ATOMIC_RELAXED, __HIP_MEMORY_SCOPE_SYSTEM);
    while (__hip_atomic_load(&bar[511], __ATOMIC_RELAXED, __HIP_MEMORY_SCOPE_SYSTEM) < (t+1)*16)
      __builtin_amdgcn_s_sleep(1);
    asm volatile("" ::: "memory");
  }
  __syncthreads();
  __builtin_amdgcn_fence(__ATOMIC_ACQUIRE, "agent");
}

// ---------------- per-wave GEMM pieces (A from global regs, B from LDS) ---
// A base / B base are already offset to this wave's (mg,kh,quad,colc) slot.
__device__ __forceinline__ f32x4 gemm1(const u16* __restrict__ A, const u16* B, f32x4 acc){
  bf16x8 af[16];
  #pragma unroll
  for (int kt=0;kt<16;++kt) af[kt] = *(const bf16x8*)(A + kt*32);
  #pragma unroll
  for (int kt=0;kt<16;++kt){
    bf16x8 b = *(const bf16x8*)(B + kt*512);
    acc = __builtin_amdgcn_mfma_f32_16x16x32_bf16(af[kt], b, acc, 0, 0, 0);
  }
  return acc;
}
__device__ __forceinline__ f32x4 gemm2(const u16* __restrict__ A1, const u16* __restrict__ A2,
                                       const u16* B1, const u16* B2, f32x4 acc){
  bf16x8 af[16], ag[16];
  #pragma unroll
  for (int kt=0;kt<16;++kt) af[kt] = *(const bf16x8*)(A1 + kt*32);
  #pragma unroll
  for (int kt=0;kt<16;++kt) ag[kt] = *(const bf16x8*)(A2 + kt*32);
  #pragma unroll
  for (int kt=0;kt<16;++kt)
    acc = __builtin_amdgcn_mfma_f32_16x16x32_bf16(af[kt], *(const bf16x8*)(B1 + kt*512), acc, 0,0,0);
  #pragma unroll
  for (int kt=0;kt<16;++kt)
    acc = __builtin_amdgcn_mfma_f32_16x16x32_bf16(ag[kt], *(const bf16x8*)(B2 + kt*512), acc, 0,0,0);
  return acc;
}

// ---------------- persistent 2-layer LSTM over 127 steps ------------------
// 256 blocks x 512 threads (8 waves = mg(4) x kh(2)); 1 block/CU, ALL CUs.
// Block owns 4 j-cols -> 16 gate rows. All 4 weight matrices LDS-resident
// (128 KB). A-fragments read straight from global h (cached; fence-refreshed),
// 16 fully-utilized 64B lines per load instruction. t=0 phase A swaps
// A<-x0, B<-Wih0 (h0=0 kills the recurrent term); t>0 one-hot term is a
// 4-element gather from the LDS Wih0 pack. c-state in cell-thread registers.
__global__ void __launch_bounds__(512, 2) lstm_kernel(
    const u16* __restrict__ P, const float* __restrict__ B0p,
    const float* __restrict__ B1p, const u16* __restrict__ x0bf,
    const int* __restrict__ tix,
    u16* __restrict__ h0bf, u16* __restrict__ h1bf,
    u16* __restrict__ hs, int* __restrict__ bar)
{
  extern __shared__ char smem[];
  u16*   Plds  = (u16*)smem;                     // 4*16384 u16 = 131072 B
  float* gates = (float*)(smem + 131072);        // [2][64][GST] f32 = 8704 B
  u16*   tixl  = (u16*)(smem + 131072 + 8704);   // [128 t][64 b] u16 = 16384 B

  const int tid  = threadIdx.x;
  const int lane = tid&63, w = tid>>6, quad = lane>>4, colc = lane&15;
  const int mg   = w>>1, kh = w&1;
  const int bid  = blockIdx.x;

  { // one-time: weights + transposed text indices -> LDS
    const bf16x8* gs = (const bf16x8*)(P + (size_t)bid*65536);
    bf16x8* gd = (bf16x8*)Plds;
    #pragma unroll
    for (int i=0;i<16;++i) gd[tid + i*512] = gs[tid + i*512];
    for (int i=tid; i<BB*128; i+=512) tixl[i] = (u16)tix[(i&63)*128 + (i>>6)];
  }

  // per-wave A/B offsets (u16 units)
  const int aoff = (mg*16 + colc)*HH + kh*512 + quad*8;
  const int boff = kh*8192 + colc*32 + quad*8;

  // cell threads: tid<256 -> (b=tid>>2, jj=tid&3)
  const int cb = tid>>2, cjj = tid&3;
  float cc0 = 0.f, cc1 = 0.f;
  float4 vb0 = {0,0,0,0}, vb1 = {0,0,0,0};
  if (tid < 256){
    vb0 = *(const float4*)(B0p + (bid*4+cjj)*4);
    vb1 = *(const float4*)(B1p + (bid*4+cjj)*4);
  }
  __syncthreads();

  #pragma unroll 1
  for (int t=0;t<LSTEPS;++t){
    const int cur = t&1, nxt = cur^1;
    // -------- Phase A: layer0 gates + cell --------
    {
      const u16* Ab = ((t==0)? x0bf : (h0bf + (size_t)cur*BHH)) + aoff;
      const u16* Bb = Plds + ((t==0)? 0 : 16384) + boff;
      f32x4 z = {0.f,0.f,0.f,0.f};
      f32x4 acc = gemm1(Ab, Bb, z);
      __syncthreads();   // prev step's phase-B gate readers done
      #pragma unroll
      for (int r=0;r<4;++r) gates[(kh*64 + mg*16 + quad*4 + r)*GST + colc] = acc[r];
    }
    __syncthreads();
    if (tid < 256){
      float gv[4];
      #pragma unroll
      for (int g=0;g<4;++g)
        gv[g] = gates[cb*GST + g*4+cjj] + gates[(64+cb)*GST + g*4+cjj];
      gv[0]+=vb0.x; gv[1]+=vb0.y; gv[2]+=vb0.z; gv[3]+=vb0.w;
      if (t>0){
        int ch = tixl[t*64 + cb];                 // one-hot: gather Wih0 col from LDS pack
        int base = (ch>>5)*512 + (ch&31);
        #pragma unroll
        for (int g=0;g<4;++g) gv[g] += b2f(Plds[base + (g*4+cjj)*32]);
      }
      cc0 = sig_(gv[1])*cc0 + sig_(gv[0])*tanh_(gv[2]);
      float hn = sig_(gv[3])*tanh_(cc0);
      unsigned hv = f2b(hn);
      unsigned ov = __shfl_xor(hv, 1);
      if ((cjj&1)==0)
        sysst32((unsigned*)(h0bf + (size_t)nxt*BHH) + (cb*HH + bid*4 + cjj)/2, hv | (ov<<16));
    }
    gridbar(bar, t);   // h0_t globally visible + L2 invalidated before layer1
    // -------- Phase B: layer1 gates + cell --------
    {
      f32x4 z = {0.f,0.f,0.f,0.f};
      f32x4 acc = gemm2(h0bf + (size_t)nxt*BHH + aoff, h1bf + (size_t)cur*BHH + aoff,
                        Plds + 2*16384 + boff,         Plds + 3*16384 + boff, z);
      #pragma unroll
      for (int r=0;r<4;++r) gates[(kh*64 + mg*16 + quad*4 + r)*GST + colc] = acc[r];
    }
    __syncthreads();
    if (tid < 256){
      float gv[4];
      #pragma unroll
      for (int g=0;g<4;++g)
        gv[g] = gates[cb*GST + g*4+cjj] + gates[(64+cb)*GST + g*4+cjj];
      gv[0]+=vb1.x; gv[1]+=vb1.y; gv[2]+=vb1.z; gv[3]+=vb1.w;
      cc1 = sig_(gv[1])*cc1 + sig_(gv[0])*tanh_(gv[2]);
      float hn = sig_(gv[3])*tanh_(cc1);
      unsigned hv = f2b(hn);
      unsigned ov = __shfl_xor(hv, 1);
      if ((cjj&1)==0){
        sysst32((unsigned*)(h1bf + (size_t)nxt*BHH) + (cb*HH + bid*4 + cjj)/2, hv | (ov<<16));
        sysst32((unsigned*)hs + (((size_t)t*BB + cb)*HH + bid*4 + cjj)/2, hv | (ov<<16));
      }
    }
    // next iteration's phase-A sync protects gates from overwrite.
  }
}

// ---------------- logits: [8128,1024] @ W_out^T (bf16 hi+lo), +b_out ------
// grid (64, 4): blockIdx.y splits the 64 n-tiles 4 ways -> 256 blocks.
__global__ void __launch_bounds__(512) logits_kernel(
    const u16* __restrict__ hs, const u16* __restrict__ Whi, const u16* __restrict__ Wlo,
    const float* __restrict__ bout, float* __restrict__ out)
{
  extern __shared__ u16 bsh[];   // 2 * 16 * 1032 u16 = 66048 B
  const int tid = threadIdx.x;
  const int w = tid>>6, lane = tid&63, quad = lane>>4, col = lane&15;
  const int mt = blockIdx.x*8 + w;
  const bool active = (mt < (LSTEPS*BB)/16);   // 508 m-tiles
  bf16x8 afr[32];
  if (active){
    const u16* ap = hs + (size_t)(mt*16+col)*HH + quad*8;
    #pragma unroll
    for (int kt=0;kt<32;++kt) afr[kt] = *(const bf16x8*)(ap + kt*32);
  }
  const int nt0 = blockIdx.y*16;
  for (int nt=nt0; nt<nt0+16; ++nt){
    __syncthreads();
    #pragma unroll
    for (int i=0;i<8;++i){
      int cid = i*512 + tid;          // 4096 chunks of 16B (hi then lo)
      int mat = cid>>11;
      int r = (cid>>7)&15, ck = cid&127;
      const u16* src = (mat? Wlo : Whi) + (size_t)(nt*16+r)*HH + ck*8;
      *(bf16x8*)(bsh + mat*16512 + r*1032 + ck*8) = *(const bf16x8*)src;
    }
    __syncthreads();
    if (active){
      f32x4 acc = {0.f,0.f,0.f,0.f};
      const u16* bh = bsh + col*1032 + quad*8;
      const u16* bl = bsh + 16512 + col*1032 + quad*8;
      #pragma unroll 8
      for (int kt=0;kt<32;++kt){
        bf16x8 b1 = *(const bf16x8*)(bh + kt*32);
        acc = __builtin_amdgcn_mfma_f32_16x16x32_bf16(afr[kt], b1, acc, 0,0,0);
        bf16x8 b2 = *(const bf16x8*)(bl + kt*32);
        acc = __builtin_amdgcn_mfma_f32_16x16x32_bf16(afr[kt], b2, acc, 0,0,0);
      }
      float bb = bout[nt*16 + col];
      #pragma unroll
      for (int r=0;r<4;++r){
        int m = mt*16 + quad*4 + r;
        int tt = m>>6, b_ = m&63;
        out[((size_t)b_*LSTEPS + tt)*HH + nt*16 + col] = acc[r] + bb;
      }
    }
  }
}

extern "C" void kernel_launch(void* const* d_in, const int* in_sizes, int n_in,
                              void* d_out, int out_size, void* d_ws, size_t ws_size,
                              hipStream_t stream) {
  const float* audio = (const float*)d_in[0];
  const int*   tix   = (const int*)  d_in[1];
  const float* Wproj = (const float*)d_in[2];
  const float* bproj = (const float*)d_in[3];
  const float* Wih0  = (const float*)d_in[4];
  const float* Whh0  = (const float*)d_in[5];
  const float* bih0  = (const float*)d_in[6];
  const float* bhh0  = (const float*)d_in[7];
  const float* Wih1  = (const float*)d_in[8];
  const float* Whh1  = (const float*)d_in[9];
  const float* bih1  = (const float*)d_in[10];
  const float* bhh1  = (const float*)d_in[11];
  const float* Wout  = (const float*)d_in[12];
  const float* bout  = (const float*)d_in[13];
  float* out = (float*)d_out;

  char* ws = (char*)d_ws;
  u16*   wP    = (u16*)  (ws + O_PACK);
  u16*   wWoHi = (u16*)  (ws + O_WOHI);
  u16*   wWoLo = (u16*)  (ws + O_WOLO);
  float* wB0p  = (float*)(ws + O_B0P);
  float* wB1p  = (float*)(ws + O_B1P);
  float* wMean = (float*)(ws + O_MEAN);
  u16*   wX0   = (u16*)  (ws + O_X0);
  u16*   wH0   = (u16*)  (ws + O_H0);
  u16*   wH1   = (u16*)  (ws + O_H1);
  u16*   wHS   = (u16*)  (ws + O_HS);
  int*   wBar  = (int*)  (ws + O_BAR);

  init_kernel<<<64, 256, 0, stream>>>(wH0, wH1, wBar);
  pool_kernel<<<BB*3, 256, 0, stream>>>(audio, wMean);
  project_kernel<<<HH, 256, 0, stream>>>(wMean, Wproj, bproj, wX0);
  pack_w_kernel<<<dim3(NB,4), 256, 0, stream>>>(Wih0, Whh0, Wih1, Whh1, wP);
  pack_bias_kernel<<<16, 256, 0, stream>>>(bih0, bhh0, bih1, bhh1, wB0p, wB1p);
  wout_kernel<<<512, 256, 0, stream>>>(Wout, wWoHi, wWoLo, HH*HH);
  lstm_kernel<<<NB, 512, 131072 + 8704 + 16384, stream>>>(
      wP, wB0p, wB1p, wX0, tix, wH0, wH1, wHS, wBar);
  logits_kernel<<<dim3(64,4), 512, 66048, stream>>>(wHS, wWoHi, wWoLo, bout, out);
}

// Round 4
// 2521.240 us; speedup vs baseline: 1.7653x; 1.6619x over previous
//
#include <hip/hip_runtime.h>
#include <hip/hip_bf16.h>

// Problem constants
#define HH     1024
#define BB     64
#define DIN    768
#define TAUD   500
#define LSTEPS 127      // 1 audio step + 126 one-hot steps
#define G4     4096
#define NB     256      // lstm blocks; each owns 4 j-columns (16 gate rows)
#define BHH    (BB*HH)
#define GST    17       // gates LDS row stride (16 + 1 pad)

typedef __attribute__((ext_vector_type(8))) short bf16x8;
typedef __attribute__((ext_vector_type(4))) float f32x4;
typedef unsigned short u16;
typedef unsigned long long u64;

__device__ __forceinline__ u16 f2b(float x){
  __hip_bfloat16 h = __float2bfloat16(x);
  return __builtin_bit_cast(u16, h);
}
__device__ __forceinline__ float b2f(u16 u){
  unsigned int x = ((unsigned int)u) << 16;
  return __builtin_bit_cast(float, x);
}
__device__ __forceinline__ float sig_(float x){ return 1.0f/(1.0f+__expf(-x)); }
__device__ __forceinline__ float tanh_(float x){
  float ax = fabsf(x);
  float e  = __expf(-2.0f*ax);
  float t  = (1.0f-e)/(1.0f+e);
  return x < 0.0f ? -t : t;
}

// ---------------- workspace layout (bytes), ~53 MB ------------------------
// R7: base = R1 kernel (harness-proven, lstm 3783us). Two targeted changes:
// (1) low-contention barrier: only 32 blocks poll the root line (leaf leaders
//     + leaf-lasts); remaining 224 poll per-leaf release flags (14/line).
//     R0 and R1 both sat at ~29us/step despite opposite cache strategies --
//     the shared root-line hammer-poll (256 pollers on one IC line) is a
//     prime suspect for ~10-20us of release latency + arrival queueing.
// (2) the agent-acquire fence (full per-XCD L2 invalidate) is issued by
//     wave 0 only, bracketed by __syncthreads: L1 is per-CU, L2 per-XCD,
//     so one invalidate per CU suffices -> 8x fewer invalidate commands.
constexpr size_t O_PACK  = 0;                                 // u16 [256][4][32 ktg][16 col][32 r]
constexpr size_t O_WOHI  = O_PACK + (size_t)NB*4*16384*2;     // bf16 [1024,1024]
constexpr size_t O_WOLO  = O_WOHI + (size_t)HH*HH*2;
constexpr size_t O_B0P   = O_WOLO + (size_t)HH*HH*2;          // f32 [1024 unit][4 g]
constexpr size_t O_B1P   = O_B0P  + G4*4;
constexpr size_t O_MEAN  = O_B1P  + G4*4;                     // f32 [64,768]
constexpr size_t O_X0    = O_MEAN + (size_t)BB*DIN*4;         // bf16 [64,1024]
constexpr size_t O_H0    = O_X0   + (size_t)BHH*2;            // bf16 [2][64][1024]
constexpr size_t O_H1    = O_H0   + (size_t)2*BHH*2;
constexpr size_t O_HS    = O_H1   + (size_t)2*BHH*2;          // bf16 [127][64][1024]
constexpr size_t O_BAR   = O_HS   + (size_t)LSTEPS*BHH*2;     // 512 ints
// bar[] map: leaf arrival bar[leaf*32] (16 leaves), leaf release
// bar[leaf*32+16], root bar[511]. All monotone counters, zeroed once.

// ---------------- init: zero h states + barrier ---------------------------
__global__ void init_kernel(u16* h0, u16* h1, int* bar){
  int i = blockIdx.x*256 + threadIdx.x;
  int st = gridDim.x*256;
  for (int k=i;k<2*BHH;k+=st){ h0[k]=0; h1[k]=0; }
  if (i < 512) bar[i] = 0;
}

// ---------------- audio mean-pool (mean is linear: pool before project) ---
__global__ void pool_kernel(const float* __restrict__ audio, float* __restrict__ mean){
  int b = blockIdx.x/3, dc = blockIdx.x%3;
  int d = dc*256 + threadIdx.x;
  const float* p = audio + (size_t)b*TAUD*DIN + d;
  float s = 0.f;
  #pragma unroll 5
  for (int t=0;t<TAUD;++t) s += p[(size_t)t*DIN];
  mean[b*DIN + d] = s*(1.0f/TAUD);
}

// ---------------- project pooled audio: x0[b,h] (fp32 math, bf16 out) -----
__global__ void project_kernel(const float* __restrict__ mean, const float* __restrict__ Wp,
                               const float* __restrict__ bp, u16* __restrict__ x0){
  __shared__ float wrow[DIN];
  __shared__ float part[256];
  int h = blockIdx.x;
  for (int i=threadIdx.x;i<DIN;i+=256) wrow[i] = Wp[(size_t)h*DIN + i];
  __syncthreads();
  int b = threadIdx.x>>2, q = threadIdx.x&3;
  const float* mr = mean + b*DIN + q*192;
  const float* wr = wrow + q*192;
  float s = 0.f;
  #pragma unroll 8
  for (int i=0;i<192;++i) s += mr[i]*wr[i];
  part[threadIdx.x] = s;
  __syncthreads();
  if (q==0){
    float v = part[threadIdx.x]+part[threadIdx.x+1]+part[threadIdx.x+2]+part[threadIdx.x+3] + bp[h];
    x0[b*HH + h] = f2b(v);
  }
}

// ---------------- pack all 4 weight matrices into per-block blobs ---------
// Per (bid,m): 16384 u16 = [32 ktg][16 col][32 r]; element = Wm[ng][ktg*32+r],
// ng = bid*4 + (col&3) + (col>>2)*1024. Per MFMA k-step a wave reads one
// contiguous 1KB line (conflict-free ds_read_b128). m: 0=Wih0 1=Whh0 2=Wih1 3=Whh1.
__global__ void pack_w_kernel(const float* __restrict__ Wih0, const float* __restrict__ Whh0,
                              const float* __restrict__ Wih1, const float* __restrict__ Whh1,
                              u16* __restrict__ P){
  int bid = blockIdx.x, m = blockIdx.y;
  const float* src = (m==0)? Wih0 : (m==1)? Whh0 : (m==2)? Wih1 : Whh1;
  u16* dst = P + ((size_t)bid*4 + m)*16384;
  for (int e = threadIdx.x; e < 16384; e += 256){
    int r = e&31, col = (e>>5)&15, ktg = e>>9;
    int ng = bid*4 + (col&3) + (col>>2)*HH;
    dst[e] = f2b(src[(size_t)ng*HH + ktg*32 + r]);
  }
}

// Packed biases: Bp[(bid*4+jj)*4+g] = b_ih[n]+b_hh[n], n = bid*4+jj+g*1024
__global__ void pack_bias_kernel(const float* bih0, const float* bhh0,
                                 const float* bih1, const float* bhh1,
                                 float* B0p, float* B1p){
  int i = blockIdx.x*256 + threadIdx.x;
  if (i < G4){
    int n = (i>>2) + (i&3)*HH;
    B0p[i] = bih0[n]+bhh0[n];
    B1p[i] = bih1[n]+bhh1[n];
  }
}

// W_out split into bf16 hi + lo for extra precision on final GEMM
__global__ void wout_kernel(const float* __restrict__ src, u16* __restrict__ hi,
                            u16* __restrict__ lo, int n){
  int i = blockIdx.x*256+threadIdx.x, st = gridDim.x*256;
  for (;i<n;i+=st){
    float v = src[i];
    u16 h = f2b(v);
    hi[i] = h;
    lo[i] = f2b(v - b2f(h));
  }
}

// ---------------- system-scope (cache-bypass, write-through) store --------
__device__ __forceinline__ void sysst32(unsigned* p, unsigned v){
  __hip_atomic_store(p, v, __ATOMIC_RELAXED, __HIP_MEMORY_SCOPE_SYSTEM);
}

// Tree barrier with hierarchical release (low line contention), then a
// single-wave agent-acquire fence (one L1+L2 invalidate per CU, not 8).
// Arrival: 16 blocks add to their leaf line; last-of-leaf adds to root.
// Release: leaf leader (arrival rank 0) + leaf last (rank 15) poll root
// (<=32 pollers); leader then writes the leaf release flag; the other 14
// blocks of the leaf poll that flag. s_sleep(4) backoff everywhere.
__device__ __forceinline__ void gridbar(int* bar, int t){
  __syncthreads();   // drains vmcnt(0): all sc0sc1 h-stores at coherence point
  if (threadIdx.x==0){
    int leaf = blockIdx.x>>4;
    int a = __hip_atomic_fetch_add(&bar[leaf*32], 1, __ATOMIC_RELAXED, __HIP_MEMORY_SCOPE_SYSTEM);
    int r = a - t*16;                  // arrival rank within leaf: 0..15
    if (r == 15)
      __hip_atomic_fetch_add(&bar[511], 1, __ATOMIC_RELAXED, __HIP_MEMORY_SCOPE_SYSTEM);
    if (r == 0 || r == 15){
      while (__hip_atomic_load(&bar[511], __ATOMIC_RELAXED, __HIP_MEMORY_SCOPE_SYSTEM) < (t+1)*16)
        __builtin_amdgcn_s_sleep(4);
      if (r == 0)
        __hip_atomic_store(&bar[leaf*32+16], t+1, __ATOMIC_RELAXED, __HIP_MEMORY_SCOPE_SYSTEM);
    } else {
      while (__hip_atomic_load(&bar[leaf*32+16], __ATOMIC_RELAXED, __HIP_MEMORY_SCOPE_SYSTEM) < t+1)
        __builtin_amdgcn_s_sleep(4);
    }
    asm volatile("" ::: "memory");
  }
  __syncthreads();
  if (threadIdx.x < 64)
    __builtin_amdgcn_fence(__ATOMIC_ACQUIRE, "agent");   // wave 0 only: one inv/CU
  __syncthreads();
}

// ---------------- per-wave GEMM pieces (A from global regs, B from LDS) ---
__device__ __forceinline__ f32x4 gemm1(const u16* __restrict__ A, const u16* B, f32x4 acc){
  bf16x8 af[16];
  #pragma unroll
  for (int kt=0;kt<16;++kt) af[kt] = *(const bf16x8*)(A + kt*32);
  #pragma unroll
  for (int kt=0;kt<16;++kt){
    bf16x8 b = *(const bf16x8*)(B + kt*512);
    acc = __builtin_amdgcn_mfma_f32_16x16x32_bf16(af[kt], b, acc, 0, 0, 0);
  }
  return acc;
}
__device__ __forceinline__ f32x4 gemm2(const u16* __restrict__ A1, const u16* __restrict__ A2,
                                       const u16* B1, const u16* B2, f32x4 acc){
  bf16x8 af[16], ag[16];
  #pragma unroll
  for (int kt=0;kt<16;++kt) af[kt] = *(const bf16x8*)(A1 + kt*32);
  #pragma unroll
  for (int kt=0;kt<16;++kt) ag[kt] = *(const bf16x8*)(A2 + kt*32);
  #pragma unroll
  for (int kt=0;kt<16;++kt)
    acc = __builtin_amdgcn_mfma_f32_16x16x32_bf16(af[kt], *(const bf16x8*)(B1 + kt*512), acc, 0,0,0);
  #pragma unroll
  for (int kt=0;kt<16;++kt)
    acc = __builtin_amdgcn_mfma_f32_16x16x32_bf16(ag[kt], *(const bf16x8*)(B2 + kt*512), acc, 0,0,0);
  return acc;
}

// ---------------- persistent 2-layer LSTM over 127 steps ------------------
// 256 blocks x 512 threads (8 waves = mg(4) x kh(2)); 1 block/CU, ALL CUs.
// Block owns 4 j-cols -> 16 gate rows. All 4 weight matrices LDS-resident
// (128 KB). A-fragments read straight from global h (cached; fence-refreshed),
// 16 fully-utilized 64B lines per load instruction. t=0 phase A swaps
// A<-x0, B<-Wih0 (h0=0 kills the recurrent term); t>0 one-hot term is a
// 4-element gather from the LDS Wih0 pack. c-state in cell-thread registers.
__global__ void __launch_bounds__(512, 2) lstm_kernel(
    const u16* __restrict__ P, const float* __restrict__ B0p,
    const float* __restrict__ B1p, const u16* __restrict__ x0bf,
    const int* __restrict__ tix,
    u16* __restrict__ h0bf, u16* __restrict__ h1bf,
    u16* __restrict__ hs, int* __restrict__ bar)
{
  extern __shared__ char smem[];
  u16*   Plds  = (u16*)smem;                     // 4*16384 u16 = 131072 B
  float* gates = (float*)(smem + 131072);        // [2][64][GST] f32 = 8704 B
  u16*   tixl  = (u16*)(smem + 131072 + 8704);   // [128 t][64 b] u16 = 16384 B

  const int tid  = threadIdx.x;
  const int lane = tid&63, w = tid>>6, quad = lane>>4, colc = lane&15;
  const int mg   = w>>1, kh = w&1;
  const int bid  = blockIdx.x;

  { // one-time: weights + transposed text indices -> LDS
    const bf16x8* gs = (const bf16x8*)(P + (size_t)bid*65536);
    bf16x8* gd = (bf16x8*)Plds;
    #pragma unroll
    for (int i=0;i<16;++i) gd[tid + i*512] = gs[tid + i*512];
    for (int i=tid; i<BB*128; i+=512) tixl[i] = (u16)tix[(i&63)*128 + (i>>6)];
  }

  // per-wave A/B offsets (u16 units)
  const int aoff = (mg*16 + colc)*HH + kh*512 + quad*8;
  const int boff = kh*8192 + colc*32 + quad*8;

  // cell threads: tid<256 -> (b=tid>>2, jj=tid&3)
  const int cb = tid>>2, cjj = tid&3;
  float cc0 = 0.f, cc1 = 0.f;
  float4 vb0 = {0,0,0,0}, vb1 = {0,0,0,0};
  if (tid < 256){
    vb0 = *(const float4*)(B0p + (bid*4+cjj)*4);
    vb1 = *(const float4*)(B1p + (bid*4+cjj)*4);
  }
  __syncthreads();

  #pragma unroll 1
  for (int t=0;t<LSTEPS;++t){
    const int cur = t&1, nxt = cur^1;
    // -------- Phase A: layer0 gates + cell --------
    {
      const u16* Ab = ((t==0)? x0bf : (h0bf + (size_t)cur*BHH)) + aoff;
      const u16* Bb = Plds + ((t==0)? 0 : 16384) + boff;
      f32x4 z = {0.f,0.f,0.f,0.f};
      f32x4 acc = gemm1(Ab, Bb, z);
      __syncthreads();   // prev step's phase-B gate readers done
      #pragma unroll
      for (int r=0;r<4;++r) gates[(kh*64 + mg*16 + quad*4 + r)*GST + colc] = acc[r];
    }
    __syncthreads();
    if (tid < 256){
      float gv[4];
      #pragma unroll
      for (int g=0;g<4;++g)
        gv[g] = gates[cb*GST + g*4+cjj] + gates[(64+cb)*GST + g*4+cjj];
      gv[0]+=vb0.x; gv[1]+=vb0.y; gv[2]+=vb0.z; gv[3]+=vb0.w;
      if (t>0){
        int ch = tixl[t*64 + cb];                 // one-hot: gather Wih0 col from LDS pack
        int base = (ch>>5)*512 + (ch&31);
        #pragma unroll
        for (int g=0;g<4;++g) gv[g] += b2f(Plds[base + (g*4+cjj)*32]);
      }
      cc0 = sig_(gv[1])*cc0 + sig_(gv[0])*tanh_(gv[2]);
      float hn = sig_(gv[3])*tanh_(cc0);
      unsigned hv = f2b(hn);
      unsigned ov = __shfl_xor(hv, 1);
      if ((cjj&1)==0)
        sysst32((unsigned*)(h0bf + (size_t)nxt*BHH) + (cb*HH + bid*4 + cjj)/2, hv | (ov<<16));
    }
    gridbar(bar, t);   // h0_t globally visible + caches refreshed before layer1
    // -------- Phase B: layer1 gates + cell --------
    {
      f32x4 z = {0.f,0.f,0.f,0.f};
      f32x4 acc = gemm2(h0bf + (size_t)nxt*BHH + aoff, h1bf + (size_t)cur*BHH + aoff,
                        Plds + 2*16384 + boff,         Plds + 3*16384 + boff, z);
      #pragma unroll
      for (int r=0;r<4;++r) gates[(kh*64 + mg*16 + quad*4 + r)*GST + colc] = acc[r];
    }
    __syncthreads();
    if (tid < 256){
      float gv[4];
      #pragma unroll
      for (int g=0;g<4;++g)
        gv[g] = gates[cb*GST + g*4+cjj] + gates[(64+cb)*GST + g*4+cjj];
      gv[0]+=vb1.x; gv[1]+=vb1.y; gv[2]+=vb1.z; gv[3]+=vb1.w;
      cc1 = sig_(gv[1])*cc1 + sig_(gv[0])*tanh_(gv[2]);
      float hn = sig_(gv[3])*tanh_(cc1);
      unsigned hv = f2b(hn);
      unsigned ov = __shfl_xor(hv, 1);
      if ((cjj&1)==0){
        sysst32((unsigned*)(h1bf + (size_t)nxt*BHH) + (cb*HH + bid*4 + cjj)/2, hv | (ov<<16));
        sysst32((unsigned*)hs + (((size_t)t*BB + cb)*HH + bid*4 + cjj)/2, hv | (ov<<16));
      }
    }
    // next iteration's phase-A sync protects gates from overwrite.
  }
}

// ---------------- logits: [8128,1024] @ W_out^T (bf16 hi+lo), +b_out ------
// grid (64, 4): blockIdx.y splits the 64 n-tiles 4 ways -> 256 blocks.
__global__ void __launch_bounds__(512) logits_kernel(
    const u16* __restrict__ hs, const u16* __restrict__ Whi, const u16* __restrict__ Wlo,
    const float* __restrict__ bout, float* __restrict__ out)
{
  extern __shared__ u16 bsh[];   // 2 * 16 * 1032 u16 = 66048 B
  const int tid = threadIdx.x;
  const int w = tid>>6, lane = tid&63, quad = lane>>4, col = lane&15;
  const int mt = blockIdx.x*8 + w;
  const bool active = (mt < (LSTEPS*BB)/16);   // 508 m-tiles
  bf16x8 afr[32];
  if (active){
    const u16* ap = hs + (size_t)(mt*16+col)*HH + quad*8;
    #pragma unroll
    for (int kt=0;kt<32;++kt) afr[kt] = *(const bf16x8*)(ap + kt*32);
  }
  const int nt0 = blockIdx.y*16;
  for (int nt=nt0; nt<nt0+16; ++nt){
    __syncthreads();
    #pragma unroll
    for (int i=0;i<8;++i){
      int cid = i*512 + tid;          // 4096 chunks of 16B (hi then lo)
      int mat = cid>>11;
      int r = (cid>>7)&15, ck = cid&127;
      const u16* src = (mat? Wlo : Whi) + (size_t)(nt*16+r)*HH + ck*8;
      *(bf16x8*)(bsh + mat*16512 + r*1032 + ck*8) = *(const bf16x8*)src;
    }
    __syncthreads();
    if (active){
      f32x4 acc = {0.f,0.f,0.f,0.f};
      const u16* bh = bsh + col*1032 + quad*8;
      const u16* bl = bsh + 16512 + col*1032 + quad*8;
      #pragma unroll 8
      for (int kt=0;kt<32;++kt){
        bf16x8 b1 = *(const bf16x8*)(bh + kt*32);
        acc = __builtin_amdgcn_mfma_f32_16x16x32_bf16(afr[kt], b1, acc, 0,0,0);
        bf16x8 b2 = *(const bf16x8*)(bl + kt*32);
        acc = __builtin_amdgcn_mfma_f32_16x16x32_bf16(afr[kt], b2, acc, 0,0,0);
      }
      float bb = bout[nt*16 + col];
      #pragma unroll
      for (int r=0;r<4;++r){
        int m = mt*16 + quad*4 + r;
        int tt = m>>6, b_ = m&63;
        out[((size_t)b_*LSTEPS + tt)*HH + nt*16 + col] = acc[r] + bb;
      }
    }
  }
}

extern "C" void kernel_launch(void* const* d_in, const int* in_sizes, int n_in,
                              void* d_out, int out_size, void* d_ws, size_t ws_size,
                              hipStream_t stream) {
  const float* audio = (const float*)d_in[0];
  const int*   tix   = (const int*)  d_in[1];
  const float* Wproj = (const float*)d_in[2];
  const float* bproj = (const float*)d_in[3];
  const float* Wih0  = (const float*)d_in[4];
  const float* Whh0  = (const float*)d_in[5];
  const float* bih0  = (const float*)d_in[6];
  const float* bhh0  = (const float*)d_in[7];
  const float* Wih1  = (const float*)d_in[8];
  const float* Whh1  = (const float*)d_in[9];
  const float* bih1  = (const float*)d_in[10];
  const float* bhh1  = (const float*)d_in[11];
  const float* Wout  = (const float*)d_in[12];
  const float* bout  = (const float*)d_in[13];
  float* out = (float*)d_out;

  char* ws = (char*)d_ws;
  u16*   wP    = (u16*)  (ws + O_PACK);
  u16*   wWoHi = (u16*)  (ws + O_WOHI);
  u16*   wWoLo = (u16*)  (ws + O_WOLO);
  float* wB0p  = (float*)(ws + O_B0P);
  float* wB1p  = (float*)(ws + O_B1P);
  float* wMean = (float*)(ws + O_MEAN);
  u16*   wX0   = (u16*)  (ws + O_X0);
  u16*   wH0   = (u16*)  (ws + O_H0);
  u16*   wH1   = (u16*)  (ws + O_H1);
  u16*   wHS   = (u16*)  (ws + O_HS);
  int*   wBar  = (int*)  (ws + O_BAR);

  init_kernel<<<64, 256, 0, stream>>>(wH0, wH1, wBar);
  pool_kernel<<<BB*3, 256, 0, stream>>>(audio, wMean);
  project_kernel<<<HH, 256, 0, stream>>>(wMean, Wproj, bproj, wX0);
  pack_w_kernel<<<dim3(NB,4), 256, 0, stream>>>(Wih0, Whh0, Wih1, Whh1, wP);
  pack_bias_kernel<<<16, 256, 0, stream>>>(bih0, bhh0, bih1, bhh1, wB0p, wB1p);
  wout_kernel<<<512, 256, 0, stream>>>(Wout, wWoHi, wWoLo, HH*HH);
  lstm_kernel<<<NB, 512, 131072 + 8704 + 16384, stream>>>(
      wP, wB0p, wB1p, wX0, tix, wH0, wH1, wHS, wBar);
  logits_kernel<<<dim3(64,4), 512, 66048, stream>>>(wHS, wWoHi, wWoLo, bout, out);
}